// Round 2
// baseline (323064.062 us; speedup 1.0000x reference)
//
#include <hip/hip_runtime.h>
#include <hip/hip_bf16.h>
#include <hip/hip_cooperative_groups.h>

namespace cg = cooperative_groups;

typedef unsigned short u16;
typedef unsigned int   u32;

#define TT    1024
#define BB    64
#define NIN   512
#define NHID  512
#define NASZ  128
#define POLW  2560      // pol columns actually used (ninp + 4*nhid)
#define NWG   128
#define NTHR  256

// ---------------- ws layout (float offsets) ----------------
// states
#define O_AHX0 0               // 2 slots x 64*128
#define O_AHC0 16384           // 64*128 (in-place)
#define O_AHX1 24576           // 2 slots
#define O_AHC1 40960
#define O_FHX0 49152           // 2 slots x 64*512
#define O_FHX1 114688          // 2 slots
#define WS_STATE_END 180224
// pol scratch
#define O_POL0 180224          // 64*2560
#define O_POL1 344064
// x double buffer (fp32)
#define O_XBUF 507904          // 2 slots x 64*512 = 65536
// canonical fp32 weights
#define O_AW0  573440          // 512*1152
#define O_AU0  1163264         // 512*128
#define O_AB0  1228800         // 512 (bih+bhh summed)
#define O_PW0  1229312         // 2560*128
#define O_PB0  1556992         // 2560
#define O_FWI0 1559552         // 512*512
#define O_FWH0 1821696         // 512*512
#define O_FB0  2083840         // 512
#define O_AW1  2084352
#define O_AU1  2674176
#define O_AB1  2739712
#define O_PW1  2740224
#define O_PB1  3067904
#define O_FWI1 3070464
#define O_FWH1 3332608
#define O_FB1  3594752
#define WS_TOTAL 3595264       // ~14.4 MB

__device__ __forceinline__ float bf2f(u16 v) {
  return __uint_as_float(((u32)v) << 16);
}
__device__ __forceinline__ u16 f2bf(float f) {
  u32 u = __float_as_uint(f);
  u32 r = (u + 0x7fffu + ((u >> 16) & 1u)) >> 16;   // RNE
  return (u16)r;
}
__device__ __forceinline__ float sigm(float x) { return 1.f / (1.f + __expf(-x)); }

// detect whether a float-tensor buffer holds fp32 (true) or bf16 (false).
// If fp32, even u16s are mantissa halves -> wild exponents when read as bf16.
__device__ bool detect_f32(const void* xv) {
  const u16* s = (const u16*)xv;
  int hits = 0;
  for (int i = 0; i < 1024; i += 2) {
    float av = fabsf(bf2f(s[i]));
    if (!(av < 1e10f)) hits++;       // also catches inf/nan
  }
  return hits > 16;
}

__device__ __forceinline__ float dot_ff(const float* a, const float* w, int n) {
  float acc = 0.f;
  #pragma unroll 4
  for (int k = 0; k < n; k += 4) {
    float4 a0 = *(const float4*)(a + k);
    float4 w0 = *(const float4*)(w + k);
    acc += a0.x*w0.x + a0.y*w0.y + a0.z*w0.z + a0.w*w0.w;
  }
  return acc;
}
__device__ __forceinline__ float dot3_ff(const float* a, const float* p, const float* w, int n) {
  float acc = 0.f;
  #pragma unroll 4
  for (int k = 0; k < n; k += 4) {
    float4 a0 = *(const float4*)(a + k);
    float4 p0 = *(const float4*)(p + k);
    float4 w0 = *(const float4*)(w + k);
    acc += (a0.x*p0.x)*w0.x + (a0.y*p0.y)*w0.y + (a0.z*p0.z)*w0.z + (a0.w*p0.w)*w0.w;
  }
  return acc;
}

__device__ __forceinline__ void conv_tensor(const void* src, float* dst, int n,
                                            bool f32, int gtid, int gstride) {
  if (f32) {
    const float* s = (const float*)src;
    for (int i = gtid; i < n; i += gstride) dst[i] = s[i];
  } else {
    const u16* s = (const u16*)src;
    for (int i = gtid; i < n; i += gstride) dst[i] = bf2f(s[i]);
  }
}

struct Params {
  const void* x;
  const void *aW_ih0, *aW_hh0, *ab_ih0, *ab_hh0, *pW0, *pb0, *fW_ih0, *fW_hh0, *fb0;
  const void *aW_ih1, *aW_hh1, *ab_ih1, *ab_hh1, *pW1, *pb1, *fW_ih1, *fW_hh1, *fb1;
  void* out;
  float* ws;
};

__global__ __launch_bounds__(NTHR, 1)
void arnn_kernel(Params p) {
  cg::grid_group grid = cg::this_grid();
  const int tid = threadIdx.x;
  const int wg  = blockIdx.x;      // 0..127
  const int gtid = wg * NTHR + tid;
  const int gstride = NWG * NTHR;
  float* ws = p.ws;

  __shared__ float sm[NTHR];

  const bool f32 = detect_f32(p.x);

  // ---- pre-loop: zero states, canonicalize weights + x(0) to fp32 in ws
  for (int i = gtid; i < WS_STATE_END; i += gstride) ws[i] = 0.f;
  conv_tensor(p.x,      ws + O_XBUF, BB * NIN, f32, gtid, gstride);   // slot 0 = x(0)
  conv_tensor(p.aW_ih0, ws + O_AW0, 512 * 1152, f32, gtid, gstride);
  conv_tensor(p.aW_hh0, ws + O_AU0, 512 * 128,  f32, gtid, gstride);
  conv_tensor(p.pW0,    ws + O_PW0, 2560 * 128, f32, gtid, gstride);
  conv_tensor(p.pb0,    ws + O_PB0, 2560,       f32, gtid, gstride);
  conv_tensor(p.fW_ih0, ws + O_FWI0, 512 * 512, f32, gtid, gstride);
  conv_tensor(p.fW_hh0, ws + O_FWH0, 512 * 512, f32, gtid, gstride);
  conv_tensor(p.fb0,    ws + O_FB0, 512,        f32, gtid, gstride);
  conv_tensor(p.aW_ih1, ws + O_AW1, 512 * 1152, f32, gtid, gstride);
  conv_tensor(p.aW_hh1, ws + O_AU1, 512 * 128,  f32, gtid, gstride);
  conv_tensor(p.pW1,    ws + O_PW1, 2560 * 128, f32, gtid, gstride);
  conv_tensor(p.pb1,    ws + O_PB1, 2560,       f32, gtid, gstride);
  conv_tensor(p.fW_ih1, ws + O_FWI1, 512 * 512, f32, gtid, gstride);
  conv_tensor(p.fW_hh1, ws + O_FWH1, 512 * 512, f32, gtid, gstride);
  conv_tensor(p.fb1,    ws + O_FB1, 512,        f32, gtid, gstride);
  // summed LSTM biases
  if (f32) {
    for (int i = gtid; i < 512; i += gstride) {
      ws[O_AB0 + i] = ((const float*)p.ab_ih0)[i] + ((const float*)p.ab_hh0)[i];
      ws[O_AB1 + i] = ((const float*)p.ab_ih1)[i] + ((const float*)p.ab_hh1)[i];
    }
  } else {
    for (int i = gtid; i < 512; i += gstride) {
      ws[O_AB0 + i] = bf2f(((const u16*)p.ab_ih0)[i]) + bf2f(((const u16*)p.ab_hh0)[i]);
      ws[O_AB1 + i] = bf2f(((const u16*)p.ab_ih1)[i]) + bf2f(((const u16*)p.ab_hh1)[i]);
    }
  }
  grid.sync();

  for (int t = 0; t < TT; ++t) {
    const int old = t & 1, nw = old ^ 1;
    float* ahx0_o = ws + O_AHX0 + old * 8192;
    float* ahx0_n = ws + O_AHX0 + nw  * 8192;
    float* ahx1_o = ws + O_AHX1 + old * 8192;
    float* ahx1_n = ws + O_AHX1 + nw  * 8192;
    float* ahc0   = ws + O_AHC0;
    float* ahc1   = ws + O_AHC1;
    float* fhx0_o = ws + O_FHX0 + old * 32768;
    float* fhx0_n = ws + O_FHX0 + nw  * 32768;
    float* fhx1_o = ws + O_FHX1 + old * 32768;
    float* fhx1_n = ws + O_FHX1 + nw  * 32768;
    float* pol0   = ws + O_POL0;
    float* pol1   = ws + O_POL1;
    const float* xt = ws + O_XBUF + old * 32768;

    // ---- P0: LSTM layer 0: g = [xt, fhx0_o, ahx1_o]@Wih.T + b + ahx0_o@Whh.T
    {
      const int j = wg, b = tid >> 2, q = tid & 3;
      const int row = q * NASZ + j;
      const float* wr = ws + O_AW0 + (size_t)row * 1152;
      float acc = ws[O_AB0 + row];
      acc += dot_ff(xt + b * NIN, wr, NIN);
      acc += dot_ff(fhx0_o + b * NHID, wr + NIN, NHID);
      acc += dot_ff(ahx1_o + b * NASZ, wr + NIN + NHID, NASZ);
      acc += dot_ff(ahx0_o + b * NASZ, ws + O_AU0 + (size_t)row * NASZ, NASZ);
      sm[tid] = acc;
      __syncthreads();
      if (tid < 64) {
        float gi = sm[tid*4+0], gf = sm[tid*4+1], gg = sm[tid*4+2], go = sm[tid*4+3];
        float c  = ahc0[tid * NASZ + j];
        float c2 = sigm(gf) * c + sigm(gi) * tanhf(gg);
        ahc0[tid * NASZ + j]   = c2;
        ahx0_n[tid * NASZ + j] = sigm(go) * tanhf(c2);
      }
    }
    grid.sync();

    // ---- P1: pol0 = ahx0_n @ pW0.T + pb0  (+ pipelined x(t+1) conversion)
    {
      const int n0 = wg * 20;
      for (int idx = tid; idx < 64 * 20; idx += NTHR) {
        int b = idx & 63, n = n0 + (idx >> 6);
        pol0[b * POLW + n] = ws[O_PB0 + n] +
            dot_ff(ahx0_n + b * NASZ, ws + O_PW0 + (size_t)n * NASZ, NASZ);
      }
      if (t + 1 < TT) {
        float* xnext = ws + O_XBUF + nw * 32768;
        size_t base = (size_t)(t + 1) * BB * NIN;
        if (f32) xnext[gtid] = ((const float*)p.x)[base + gtid];
        else     xnext[gtid] = bf2f(((const u16*)p.x)[base + gtid]);
      }
    }
    grid.sync();

    // ---- P2: aRNN layer 0
    {
      const int b = tid >> 2, c = wg * 4 + (tid & 3);
      const float* pr = pol0 + b * POLW;
      float ig = dot3_ff(xt + b * NIN, pr, ws + O_FWI0 + (size_t)c * NIN, NIN);
      float hg = dot3_ff(fhx0_o + b * NHID, pr + NIN, ws + O_FWH0 + (size_t)c * NHID, NHID);
      float v = tanhf(ig * pr[1024 + c] + ws[O_FB0 + c] * pr[2048 + c] + hg * pr[1536 + c]);
      fhx0_n[b * NHID + c] = v;
    }
    grid.sync();

    // ---- P3: LSTM layer 1: inputs [fhx0_n, fhx1_o, ahx0_n], h = ahx1_o
    {
      const int j = wg, b = tid >> 2, q = tid & 3;
      const int row = q * NASZ + j;
      const float* wr = ws + O_AW1 + (size_t)row * 1152;
      float acc = ws[O_AB1 + row];
      acc += dot_ff(fhx0_n + b * NHID, wr, NHID);
      acc += dot_ff(fhx1_o + b * NHID, wr + NHID, NHID);
      acc += dot_ff(ahx0_n + b * NASZ, wr + 2 * NHID, NASZ);
      acc += dot_ff(ahx1_o + b * NASZ, ws + O_AU1 + (size_t)row * NASZ, NASZ);
      sm[tid] = acc;
      __syncthreads();
      if (tid < 64) {
        float gi = sm[tid*4+0], gf = sm[tid*4+1], gg = sm[tid*4+2], go = sm[tid*4+3];
        float c  = ahc1[tid * NASZ + j];
        float c2 = sigm(gf) * c + sigm(gi) * tanhf(gg);
        ahc1[tid * NASZ + j]   = c2;
        ahx1_n[tid * NASZ + j] = sigm(go) * tanhf(c2);
      }
    }
    grid.sync();

    // ---- P4: pol1 = ahx1_n @ pW1.T + pb1
    {
      const int n0 = wg * 20;
      for (int idx = tid; idx < 64 * 20; idx += NTHR) {
        int b = idx & 63, n = n0 + (idx >> 6);
        pol1[b * POLW + n] = ws[O_PB1 + n] +
            dot_ff(ahx1_n + b * NASZ, ws + O_PW1 + (size_t)n * NASZ, NASZ);
      }
    }
    grid.sync();

    // ---- P5: aRNN layer 1 + output write
    {
      const int b = tid >> 2, c = wg * 4 + (tid & 3);
      const float* pr = pol1 + b * POLW;
      float ig = dot3_ff(fhx0_n + b * NHID, pr, ws + O_FWI1 + (size_t)c * NHID, NHID);
      float hg = dot3_ff(fhx1_o + b * NHID, pr + NHID, ws + O_FWH1 + (size_t)c * NHID, NHID);
      float v = tanhf(ig * pr[1024 + c] + ws[O_FB1 + c] * pr[2048 + c] + hg * pr[1536 + c]);
      fhx1_n[b * NHID + c] = v;
      size_t oi = ((size_t)t * BB + b) * NHID + c;
      if (f32) ((float*)p.out)[oi] = v;
      else     ((u16*)p.out)[oi]   = f2bf(v);
    }
    grid.sync();
  }
}

extern "C" void kernel_launch(void* const* d_in, const int* in_sizes, int n_in,
                              void* d_out, int out_size, void* d_ws, size_t ws_size,
                              hipStream_t stream) {
  Params prm;
  prm.x      = d_in[0];
  prm.aW_ih0 = d_in[1];
  prm.aW_hh0 = d_in[2];
  prm.ab_ih0 = d_in[3];
  prm.ab_hh0 = d_in[4];
  prm.pW0    = d_in[5];
  prm.pb0    = d_in[6];
  prm.fW_ih0 = d_in[7];
  prm.fW_hh0 = d_in[8];
  prm.fb0    = d_in[9];
  prm.aW_ih1 = d_in[10];
  prm.aW_hh1 = d_in[11];
  prm.ab_ih1 = d_in[12];
  prm.ab_hh1 = d_in[13];
  prm.pW1    = d_in[14];
  prm.pb1    = d_in[15];
  prm.fW_ih1 = d_in[16];
  prm.fW_hh1 = d_in[17];
  prm.fb1    = d_in[18];
  prm.out    = d_out;
  prm.ws     = (float*)d_ws;

  void* kargs[] = { (void*)&prm };
  hipLaunchCooperativeKernel((const void*)arnn_kernel, dim3(NWG), dim3(NTHR),
                             kargs, 0, stream);
}

// Round 3
// 220182.886 us; speedup vs baseline: 1.4673x; 1.4673x over previous
//
#include <hip/hip_runtime.h>
#include <hip/hip_cooperative_groups.h>

namespace cg = cooperative_groups;

#define TT    1024
#define BB    64
#define NIN   512
#define NHID  512
#define POLW  2560
#define NWG   128
#define NTHR  256

// ---------------- ws layout (float offsets): states only ----------------
#define O_AHX0 0               // 2 slots x 64*128
#define O_AHC0 16384           // 64*128
#define O_AHX1 24576           // 2 slots
#define O_AHC1 40960
#define O_FHX0 49152           // 2 slots x 64*512
#define O_FHX1 114688          // 2 slots
#define O_POL0 180224          // 64*2560
#define O_POL1 344064
#define WS_STATE_END 507904    // ~2 MB

// ---------------- LDS layout (float offsets), padded strides ----------------
// pads chosen so stride%32 == 4: the 4 q-rows land on different banks
#define L_AW0  0               // [4][1156] (1152 used)
#define L_AU0  4624            // [4][132]  (128 used)
#define L_PW0  5152            // [20][128]
#define L_FWI0 7712            // [4][516]  (512 used)
#define L_FWH0 9776            // [4][516]
#define L_AW1  11840
#define L_AU1  16464
#define L_PW1  16992
#define L_FWI1 19552
#define L_FWH1 21616
#define L_AB0  23680           // [4] summed biases
#define L_PB0  23684           // [20]
#define L_FB0  23704           // [4]
#define L_AB1  23708
#define L_PB1  23712
#define L_FB1  23732
#define L_SM   23736           // [256] gate exchange
#define LDS_FLOATS 23992       // 95,968 B

__device__ __forceinline__ float sigm(float x) { return 1.f / (1.f + __expf(-x)); }

// a: global activations, w: LDS weights. 4 independent FMA chains.
__device__ __forceinline__ float dot4(const float* a, const float* w, int n) {
  float s0 = 0.f, s1 = 0.f, s2 = 0.f, s3 = 0.f;
  #pragma unroll 8
  for (int k = 0; k < n; k += 4) {
    float4 av = *(const float4*)(a + k);
    float4 wv = *(const float4*)(w + k);
    s0 = fmaf(av.x, wv.x, s0); s1 = fmaf(av.y, wv.y, s1);
    s2 = fmaf(av.z, wv.z, s2); s3 = fmaf(av.w, wv.w, s3);
  }
  return (s0 + s1) + (s2 + s3);
}
__device__ __forceinline__ float dot3(const float* a, const float* p, const float* w, int n) {
  float s0 = 0.f, s1 = 0.f, s2 = 0.f, s3 = 0.f;
  #pragma unroll 8
  for (int k = 0; k < n; k += 4) {
    float4 av = *(const float4*)(a + k);
    float4 pv = *(const float4*)(p + k);
    float4 wv = *(const float4*)(w + k);
    s0 = fmaf(av.x * pv.x, wv.x, s0); s1 = fmaf(av.y * pv.y, wv.y, s1);
    s2 = fmaf(av.z * pv.z, wv.z, s2); s3 = fmaf(av.w * pv.w, wv.w, s3);
  }
  return (s0 + s1) + (s2 + s3);
}

struct Params {
  const float* x;
  const float *aW_ih0, *aW_hh0, *ab_ih0, *ab_hh0, *pW0, *pb0, *fW_ih0, *fW_hh0, *fb0;
  const float *aW_ih1, *aW_hh1, *ab_ih1, *ab_hh1, *pW1, *pb1, *fW_ih1, *fW_hh1, *fb1;
  float* out;
  float* ws;
};

__global__ __launch_bounds__(NTHR, 1)
void arnn_kernel(Params p) {
  cg::grid_group grid = cg::this_grid();
  extern __shared__ float lds[];
  const int tid = threadIdx.x;
  const int j   = blockIdx.x;            // WG owns unit j for LSTM, rows 20j.. for pol, 4j.. for aRNN
  float* ws = p.ws;

  // ---- preload this WG's weight slice into LDS (once) ----
  for (int i = tid; i < 4 * 1152; i += NTHR) {
    int r = i / 1152, c = i - r * 1152;
    lds[L_AW0 + r * 1156 + c] = p.aW_ih0[(size_t)(r * 128 + j) * 1152 + c];
    lds[L_AW1 + r * 1156 + c] = p.aW_ih1[(size_t)(r * 128 + j) * 1152 + c];
  }
  for (int i = tid; i < 4 * 128; i += NTHR) {
    int r = i >> 7, c = i & 127;
    lds[L_AU0 + r * 132 + c] = p.aW_hh0[(r * 128 + j) * 128 + c];
    lds[L_AU1 + r * 132 + c] = p.aW_hh1[(r * 128 + j) * 128 + c];
  }
  for (int i = tid; i < 20 * 128; i += NTHR) {
    int r = i >> 7, c = i & 127;
    lds[L_PW0 + i] = p.pW0[(size_t)(j * 20 + r) * 128 + c];
    lds[L_PW1 + i] = p.pW1[(size_t)(j * 20 + r) * 128 + c];
  }
  for (int i = tid; i < 4 * 512; i += NTHR) {
    int r = i >> 9, c = i & 511;
    lds[L_FWI0 + r * 516 + c] = p.fW_ih0[(size_t)(j * 4 + r) * 512 + c];
    lds[L_FWH0 + r * 516 + c] = p.fW_hh0[(size_t)(j * 4 + r) * 512 + c];
    lds[L_FWI1 + r * 516 + c] = p.fW_ih1[(size_t)(j * 4 + r) * 512 + c];
    lds[L_FWH1 + r * 516 + c] = p.fW_hh1[(size_t)(j * 4 + r) * 512 + c];
  }
  if (tid < 4) {
    lds[L_AB0 + tid] = p.ab_ih0[tid * 128 + j] + p.ab_hh0[tid * 128 + j];
    lds[L_AB1 + tid] = p.ab_ih1[tid * 128 + j] + p.ab_hh1[tid * 128 + j];
    lds[L_FB0 + tid] = p.fb0[j * 4 + tid];
    lds[L_FB1 + tid] = p.fb1[j * 4 + tid];
  }
  if (tid < 20) {
    lds[L_PB0 + tid] = p.pb0[j * 20 + tid];
    lds[L_PB1 + tid] = p.pb1[j * 20 + tid];
  }
  // zero recurrent state
  for (int i = j * NTHR + tid; i < WS_STATE_END; i += NWG * NTHR) ws[i] = 0.f;
  __syncthreads();
  grid.sync();

  for (int t = 0; t < TT; ++t) {
    const int old = t & 1, nw = old ^ 1;
    float* ahx0_o = ws + O_AHX0 + old * 8192;
    float* ahx0_n = ws + O_AHX0 + nw  * 8192;
    float* ahx1_o = ws + O_AHX1 + old * 8192;
    float* ahx1_n = ws + O_AHX1 + nw  * 8192;
    float* ahc0   = ws + O_AHC0;
    float* ahc1   = ws + O_AHC1;
    float* fhx0_o = ws + O_FHX0 + old * 32768;
    float* fhx0_n = ws + O_FHX0 + nw  * 32768;
    float* fhx1_o = ws + O_FHX1 + old * 32768;
    float* fhx1_n = ws + O_FHX1 + nw  * 32768;
    float* pol0   = ws + O_POL0;
    float* pol1   = ws + O_POL1;
    const float* xt = p.x + (size_t)t * BB * NIN;

    // ---- P0: LSTM0 gates: [xt, fhx0_o, ahx1_o] @ Wih.T + b + ahx0_o @ Whh.T
    {
      const int b = tid >> 2, q = tid & 3;
      const float* w = &lds[L_AW0 + q * 1156];
      float acc = lds[L_AB0 + q];
      acc += dot4(xt     + b * NIN,  w,        NIN);
      acc += dot4(fhx0_o + b * NHID, w + 512,  NHID);
      acc += dot4(ahx1_o + b * 128,  w + 1024, 128);
      acc += dot4(ahx0_o + b * 128,  &lds[L_AU0 + q * 132], 128);
      lds[L_SM + tid] = acc;
      __syncthreads();
      if (tid < 64) {
        float gi = lds[L_SM + tid*4+0], gf = lds[L_SM + tid*4+1];
        float gg = lds[L_SM + tid*4+2], go = lds[L_SM + tid*4+3];
        float c  = ahc0[tid * 128 + j];
        float c2 = sigm(gf) * c + sigm(gi) * tanhf(gg);
        ahc0[tid * 128 + j]   = c2;
        ahx0_n[tid * 128 + j] = sigm(go) * tanhf(c2);
      }
    }
    grid.sync();

    // ---- P1: pol0 rows 20j..20j+19
    {
      for (int idx = tid; idx < 64 * 20; idx += NTHR) {
        int b = idx & 63, nn = idx >> 6;
        pol0[b * POLW + j * 20 + nn] = lds[L_PB0 + nn] +
            dot4(ahx0_n + b * 128, &lds[L_PW0 + nn * 128], 128);
      }
    }
    grid.sync();

    // ---- P2: aRNN0: c = 4j + (tid&3)
    {
      const int b = tid >> 2, c4 = tid & 3, c = j * 4 + c4;
      const float* pr = pol0 + b * POLW;
      float ig = dot3(xt     + b * NIN,  pr,       &lds[L_FWI0 + c4 * 516], NIN);
      float hg = dot3(fhx0_o + b * NHID, pr + 512, &lds[L_FWH0 + c4 * 516], NHID);
      float v = tanhf(ig * pr[1024 + c] + lds[L_FB0 + c4] * pr[2048 + c] + hg * pr[1536 + c]);
      fhx0_n[b * NHID + c] = v;
    }
    grid.sync();

    // ---- P3: LSTM1 gates: [fhx0_n, fhx1_o, ahx0_n] @ Wih.T + b + ahx1_o @ Whh.T
    {
      const int b = tid >> 2, q = tid & 3;
      const float* w = &lds[L_AW1 + q * 1156];
      float acc = lds[L_AB1 + q];
      acc += dot4(fhx0_n + b * NHID, w,        NHID);
      acc += dot4(fhx1_o + b * NHID, w + 512,  NHID);
      acc += dot4(ahx0_n + b * 128,  w + 1024, 128);
      acc += dot4(ahx1_o + b * 128,  &lds[L_AU1 + q * 132], 128);
      lds[L_SM + tid] = acc;
      __syncthreads();
      if (tid < 64) {
        float gi = lds[L_SM + tid*4+0], gf = lds[L_SM + tid*4+1];
        float gg = lds[L_SM + tid*4+2], go = lds[L_SM + tid*4+3];
        float c  = ahc1[tid * 128 + j];
        float c2 = sigm(gf) * c + sigm(gi) * tanhf(gg);
        ahc1[tid * 128 + j]   = c2;
        ahx1_n[tid * 128 + j] = sigm(go) * tanhf(c2);
      }
    }
    grid.sync();

    // ---- P4: pol1 rows 20j..20j+19
    {
      for (int idx = tid; idx < 64 * 20; idx += NTHR) {
        int b = idx & 63, nn = idx >> 6;
        pol1[b * POLW + j * 20 + nn] = lds[L_PB1 + nn] +
            dot4(ahx1_n + b * 128, &lds[L_PW1 + nn * 128], 128);
      }
    }
    grid.sync();

    // ---- P5: aRNN1 + output
    {
      const int b = tid >> 2, c4 = tid & 3, c = j * 4 + c4;
      const float* pr = pol1 + b * POLW;
      float ig = dot3(fhx0_n + b * NHID, pr,       &lds[L_FWI1 + c4 * 516], NHID);
      float hg = dot3(fhx1_o + b * NHID, pr + 512, &lds[L_FWH1 + c4 * 516], NHID);
      float v = tanhf(ig * pr[1024 + c] + lds[L_FB1 + c4] * pr[2048 + c] + hg * pr[1536 + c]);
      fhx1_n[b * NHID + c] = v;
      p.out[((size_t)t * BB + b) * NHID + c] = v;
    }
    grid.sync();
  }
}

extern "C" void kernel_launch(void* const* d_in, const int* in_sizes, int n_in,
                              void* d_out, int out_size, void* d_ws, size_t ws_size,
                              hipStream_t stream) {
  Params prm;
  prm.x      = (const float*)d_in[0];
  prm.aW_ih0 = (const float*)d_in[1];
  prm.aW_hh0 = (const float*)d_in[2];
  prm.ab_ih0 = (const float*)d_in[3];
  prm.ab_hh0 = (const float*)d_in[4];
  prm.pW0    = (const float*)d_in[5];
  prm.pb0    = (const float*)d_in[6];
  prm.fW_ih0 = (const float*)d_in[7];
  prm.fW_hh0 = (const float*)d_in[8];
  prm.fb0    = (const float*)d_in[9];
  prm.aW_ih1 = (const float*)d_in[10];
  prm.aW_hh1 = (const float*)d_in[11];
  prm.ab_ih1 = (const float*)d_in[12];
  prm.ab_hh1 = (const float*)d_in[13];
  prm.pW1    = (const float*)d_in[14];
  prm.pb1    = (const float*)d_in[15];
  prm.fW_ih1 = (const float*)d_in[16];
  prm.fW_hh1 = (const float*)d_in[17];
  prm.fb1    = (const float*)d_in[18];
  prm.out    = (float*)d_out;
  prm.ws     = (float*)d_ws;

  void* kargs[] = { (void*)&prm };
  hipLaunchCooperativeKernel((const void*)arnn_kernel, dim3(NWG), dim3(NTHR),
                             kargs, LDS_FLOATS * 4, stream);
}